// Round 1
// 1405.691 us; speedup vs baseline: 1.1146x; 1.1146x over previous
//
#include <hip/hip_runtime.h>

typedef unsigned short ushort_t;
typedef __bf16 bf16x8 __attribute__((ext_vector_type(8)));
typedef float f32x4 __attribute__((ext_vector_type(4)));

#define NWIN 2048
#define QKV_LD 1536
#define ATT_SCALE 0.125f

__device__ inline ushort_t f2bf(float f) {
    unsigned u = __float_as_uint(f);
    u += 0x7fffu + ((u >> 16) & 1u);      // round-to-nearest-even
    return (ushort_t)(u >> 16);
}
__device__ inline float bl(unsigned u) { return __uint_as_float(u << 16); }
__device__ inline float bh(unsigned u) { return __uint_as_float(u & 0xffff0000u); }
__device__ inline void unpack8(uint4 u, float* f) {
    f[0] = bl(u.x); f[1] = bh(u.x); f[2] = bl(u.y); f[3] = bh(u.y);
    f[4] = bl(u.z); f[5] = bh(u.z); f[6] = bl(u.w); f[7] = bh(u.w);
}
__device__ inline float clampn(float n) { return fminf(fmaxf(n, 1e-20f), 1e10f); }

// async 16B global -> LDS (wave-uniform base + lane*16 semantics)
__device__ inline void async_copy16(const void* g, void* l) {
    __builtin_amdgcn_global_load_lds(
        (const __attribute__((address_space(1))) unsigned*)g,
        (__attribute__((address_space(3))) unsigned*)l, 16, 0, 0);
}

// ---------------------------------------------------------------------------
// fp32 -> bf16 converters
// ---------------------------------------------------------------------------
__global__ __launch_bounds__(256) void convert_x_kernel(
    const float* __restrict__ x, ushort_t* __restrict__ xbf)
{
    size_t i = ((size_t)blockIdx.x * 256 + threadIdx.x) * 8;
    float4 a = *(const float4*)&x[i];
    float4 b = *(const float4*)&x[i + 4];
    union { ushort_t us[8]; uint4 v; } p;
    p.us[0] = f2bf(a.x); p.us[1] = f2bf(a.y); p.us[2] = f2bf(a.z); p.us[3] = f2bf(a.w);
    p.us[4] = f2bf(b.x); p.us[5] = f2bf(b.y); p.us[6] = f2bf(b.z); p.us[7] = f2bf(b.w);
    *(uint4*)&xbf[i] = p.v;
}

__global__ __launch_bounds__(256) void convert_w_kernel(
    const float* __restrict__ wq, const float* __restrict__ wkv,
    ushort_t* __restrict__ wqkvbf)
{
    size_t i = ((size_t)blockIdx.x * 256 + threadIdx.x) * 8;   // 786432 total
    const float* src = (i < 262144) ? (wq + i) : (wkv + (i - 262144));
    float4 a = *(const float4*)src;
    float4 b = *(const float4*)(src + 4);
    union { ushort_t us[8]; uint4 v; } p;
    p.us[0] = f2bf(a.x); p.us[1] = f2bf(a.y); p.us[2] = f2bf(a.z); p.us[3] = f2bf(a.w);
    p.us[4] = f2bf(b.x); p.us[5] = f2bf(b.y); p.us[6] = f2bf(b.z); p.us[7] = f2bf(b.w);
    *(uint4*)&wqkvbf[i] = p.v;
}

// ---------------------------------------------------------------------------
// Bias expand: table[225][8] -> bias_full[8][64][64]  (128 KB, L2-resident)
// ---------------------------------------------------------------------------
__global__ __launch_bounds__(256) void bias_expand_kernel(
    const float* __restrict__ table, float* __restrict__ bias_full)
{
    int t = blockIdx.x * 256 + threadIdx.x;     // 32768 total
    int h = t >> 12, i = (t >> 6) & 63, j = t & 63;
    int idx = ((i >> 3) - (j >> 3) + 7) * 15 + ((i & 7) - (j & 7) + 7);
    bias_full[t] = table[idx * 8 + h];
}

// ---------------------------------------------------------------------------
// Kernel 1: per-window mult map = shadow * dino * plane * cc * mm  [B,64,64]
// (unchanged — correct)
// ---------------------------------------------------------------------------
__global__ __launch_bounds__(256) void mult_kernel(
    const float* __restrict__ dino, const float* __restrict__ point,
    const float* __restrict__ sdf, const float* __restrict__ normal,
    const float* __restrict__ smask, const float* __restrict__ cmask,
    float* __restrict__ multo)
{
    __shared__ float chs[64][68];
    __shared__ float sdfs[64][20];
    __shared__ float pts[64][4];
    __shared__ float nrs[64][4];
    __shared__ float cls[64][12];
    __shared__ float smc[64];
    __shared__ float dinv[64];
    __shared__ float sinv[64];
    __shared__ float rpart[4][64];

    int b = blockIdx.x;
    int t = threadIdx.x;
    size_t rbase = (size_t)b * 64;

    if (t < 64) {
        int i = t;
        pts[i][0] = point[(rbase + i) * 3 + 0];
        pts[i][1] = point[(rbase + i) * 3 + 1];
        pts[i][2] = point[(rbase + i) * 3 + 2];
        nrs[i][0] = normal[(rbase + i) * 3 + 0];
        nrs[i][1] = normal[(rbase + i) * 3 + 1];
        nrs[i][2] = normal[(rbase + i) * 3 + 2];
        smc[i] = (smask[rbase + i] < 0.1f) ? 1.0f : 2.0f;
    } else if (t < 128) {
        int i = t - 64;
        float4 c0 = *(const float4*)&cmask[(rbase + i) * 8];
        float4 c1 = *(const float4*)&cmask[(rbase + i) * 8 + 4];
        cls[i][0] = c0.x; cls[i][1] = c0.y; cls[i][2] = c0.z; cls[i][3] = c0.w;
        cls[i][4] = c1.x; cls[i][5] = c1.y; cls[i][6] = c1.z; cls[i][7] = c1.w;
    } else if (t < 192) {
        int i = t - 128;
        float ss = 0.f;
        #pragma unroll
        for (int w = 0; w < 4; ++w) {
            float4 s = *(const float4*)&sdf[(rbase + i) * 16 + w * 4];
            *(float4*)&sdfs[i][w * 4] = s;
            ss += s.x * s.x + s.y * s.y + s.z * s.z + s.w * s.w;
        }
        sinv[i] = 1.0f / clampn(sqrtf(ss));
    }
    {
        int i = t & 63, part = t >> 6;
        const float* dr = dino + (rbase + i) * 384 + part * 96;
        float ss = 0.f;
        for (int d = 0; d < 96; d += 4) {
            float4 v = *(const float4*)&dr[d];
            ss += v.x * v.x + v.y * v.y + v.z * v.z + v.w * v.w;
        }
        rpart[part][i] = ss;
    }
    __syncthreads();
    if (t < 64) {
        float s = rpart[0][t] + rpart[1][t] + rpart[2][t] + rpart[3][t];
        dinv[t] = 1.0f / clampn(sqrtf(s));
    }

    int ti = t >> 4, tj = t & 15;
    int i0 = ti * 4;
    int li = t >> 2, d4 = t & 3;

    float acc[4][4] = {};
    for (int ch = 0; ch < 6; ++ch) {
        __syncthreads();
        const float* dr = dino + (rbase + li) * 384 + ch * 64 + d4 * 16;
        #pragma unroll
        for (int w = 0; w < 4; ++w)
            *(float4*)&chs[li][d4 * 16 + w * 4] = *(const float4*)&dr[w * 4];
        __syncthreads();
        #pragma unroll 4
        for (int d = 0; d < 64; d += 4) {
            float qa[4][4], kb[4][4];
            #pragma unroll
            for (int ii = 0; ii < 4; ++ii) *(float4*)qa[ii] = *(const float4*)&chs[i0 + ii][d];
            #pragma unroll
            for (int jj = 0; jj < 4; ++jj) *(float4*)kb[jj] = *(const float4*)&chs[tj + jj * 16][d];
            #pragma unroll
            for (int ii = 0; ii < 4; ++ii)
                #pragma unroll
                for (int jj = 0; jj < 4; ++jj)
                    #pragma unroll
                    for (int e = 0; e < 4; ++e)
                        acc[ii][jj] = fmaf(qa[ii][e], kb[jj][e], acc[ii][jj]);
        }
    }

    #pragma unroll
    for (int ii = 0; ii < 4; ++ii) {
        int i = i0 + ii;
        float sdI[16];
        #pragma unroll
        for (int w = 0; w < 4; ++w) *(float4*)&sdI[w * 4] = *(const float4*)&sdfs[i][w * 4];
        float pix = pts[i][0], piy = pts[i][1], piz = pts[i][2];
        float nix = nrs[i][0], niy = nrs[i][1], niz = nrs[i][2];
        float clI[8];
        *(float4*)&clI[0] = *(const float4*)&cls[i][0];
        *(float4*)&clI[4] = *(const float4*)&cls[i][4];
        float smci = smc[i], dvi = dinv[i], svi = sinv[i];
        #pragma unroll
        for (int jj = 0; jj < 4; ++jj) {
            int j = tj + jj * 16;
            float sd = 0.f;
            #pragma unroll
            for (int w = 0; w < 4; ++w) {
                float4 sj = *(const float4*)&sdfs[j][w * 4];
                sd += sdI[w * 4 + 0] * sj.x + sdI[w * 4 + 1] * sj.y +
                      sdI[w * 4 + 2] * sj.z + sdI[w * 4 + 3] * sj.w;
            }
            sd *= svi * sinv[j];
            float shadow = 1.0f - fminf(fmaxf(sd, 0.f), 1.f);
            float dd = acc[ii][jj] * dvi * dinv[j];
            float dmap = fminf(fmaxf(dd, 0.f), 1e10f);
            float dx = pix - pts[j][0], dy = piy - pts[j][1], dz = piz - pts[j][2];
            float Pij = fabsf(dx * nix + dy * niy + dz * niz);
            float Pji = fabsf(dx * nrs[j][0] + dy * nrs[j][1] + dz * nrs[j][2]);
            float plane = __expf(-0.5f * (Pij + Pji));
            float4 cj0 = *(const float4*)&cls[j][0];
            float4 cj1 = *(const float4*)&cls[j][4];
            float cc = clI[0] * cj0.x + clI[1] * cj0.y + clI[2] * cj0.z + clI[3] * cj0.w +
                       clI[4] * cj1.x + clI[5] * cj1.y + clI[6] * cj1.z + clI[7] * cj1.w;
            float mm = (smci * smc[j] == 2.0f) ? 1.0f : 0.2f;
            multo[(size_t)b * 4096 + (size_t)i * 64 + j] = shadow * dmap * plane * cc * mm;
        }
    }
}

// ---------------------------------------------------------------------------
// Kernel 2: qkv = x_bf16 @ wqkv_bf16^T + bias  (MFMA, m97 structure)
// (unchanged)
// ---------------------------------------------------------------------------
__global__ __launch_bounds__(256) void gemm_qkv_mfma(
    const ushort_t* __restrict__ xbf, const ushort_t* __restrict__ wqkvbf,
    const float* __restrict__ bq, const float* __restrict__ bkv,
    ushort_t* __restrict__ qkv)
{
    __shared__ uint4 AsU[512];   // 128 rows x 32 k, bf16, chunk = m*4 + (kg ^ ((m>>1)&3))
    __shared__ uint4 BsU[512];

    int bid = blockIdx.x;
    int bx = bid % 12, by = bid / 12;
    int row0 = by * 128, col0 = bx * 128;

    int t = threadIdx.x;
    int wave = t >> 6, lane = t & 63;
    int wr = wave >> 1, wc = wave & 1;
    int l15 = lane & 15, kq = lane >> 4;

    f32x4 zero = {0.f, 0.f, 0.f, 0.f};
    f32x4 acc[4][4];
    #pragma unroll
    for (int i = 0; i < 4; ++i)
        #pragma unroll
        for (int j = 0; j < 4; ++j) acc[i][j] = zero;

    for (int k0 = 0; k0 < 512; k0 += 32) {
        #pragma unroll
        for (int q = 0; q < 2; ++q) {
            int c = wave * 128 + q * 64 + lane;
            int m = c >> 2, kg = (c & 3) ^ ((m >> 1) & 3);
            async_copy16(xbf + (size_t)(row0 + m) * 512 + k0 + kg * 8, &AsU[c]);
            async_copy16(wqkvbf + (size_t)(col0 + m) * 512 + k0 + kg * 8, &BsU[c]);
        }
        __syncthreads();
        bf16x8 af[4], bf[4];
        #pragma unroll
        for (int ii = 0; ii < 4; ++ii) {
            int M = wr * 64 + ii * 16 + l15;
            af[ii] = *(bf16x8*)&AsU[M * 4 + (kq ^ ((M >> 1) & 3))];
            int Nn = wc * 64 + ii * 16 + l15;
            bf[ii] = *(bf16x8*)&BsU[Nn * 4 + (kq ^ ((Nn >> 1) & 3))];
        }
        #pragma unroll
        for (int ii = 0; ii < 4; ++ii)
            #pragma unroll
            for (int jj = 0; jj < 4; ++jj)
                acc[ii][jj] = __builtin_amdgcn_mfma_f32_16x16x32_bf16(
                    af[ii], bf[jj], acc[ii][jj], 0, 0, 0);
        __syncthreads();
    }

    const float* bq_ = bq;
    const float* bkv_ = bkv;
    int crow = kq * 4, ccol = l15;
    #pragma unroll
    for (int ii = 0; ii < 4; ++ii) {
        #pragma unroll
        for (int jj = 0; jj < 4; ++jj) {
            int row = row0 + wr * 64 + ii * 16 + crow;
            int col = col0 + wc * 64 + jj * 16 + ccol;
            float bval = (bx < 4) ? bq_[col] : bkv_[col - 512];
            #pragma unroll
            for (int r = 0; r < 4; ++r)
                qkv[(size_t)(row + r) * QKV_LD + col] = f2bf(acc[ii][jj][r] + bval);
        }
    }
}

// ---------------------------------------------------------------------------
// Kernel 3: per-window attention — MFMA rewrite.
// Block = 4 waves. Per head: each wave owns 16 Q rows.
//   QK^T: A-frag = Q rows (direct global, already [row][k-contig] bf16),
//         B-frag = K rows. 8 MFMAs/wave.
//   Softmax in-register on C layout (row=(lane>>4)*4+r, col=lane&15):
//         row-reduce = 4x shfl_xor over the 16-lane column group.
//         logits = acc * (SCALE*mult)[LDS] + bias_full[h][i][j] (global, L2).
//   P stored UNNORMALIZED bf16 in per-wave LDS (1/sum folded into epilogue).
//   V^T staged cooperatively in LDS per head; PV: A=P, B=V^T. 8 MFMAs/wave.
// LDS 35.3 KB -> 4 blocks/CU (16 waves/CU).
// ---------------------------------------------------------------------------
__global__ __launch_bounds__(256) void attn_mfma_kernel(
    ushort_t* qkv, const float* __restrict__ mult, const float* __restrict__ bias_full)
{
    __shared__ float multS[64][66];          // SCALE*mult, pad 66 -> 2-way (free)
    __shared__ ushort_t vt[64][72];          // V^T[d][j], 144B rows (16B-aligned b128)
    __shared__ ushort_t ps[4][16][72];       // per-wave unnormalized P (bf16)

    int b = blockIdx.x, t = threadIdx.x;
    int wave = t >> 6, lane = t & 63;
    int l15 = lane & 15, g = lane >> 4;
    size_t base = (size_t)b * 64 * QKV_LD;
    const int iw0 = wave * 16;

    // stage SCALE*mult (coalesced; consumed after first in-loop barrier)
    {
        const float* ms = mult + (size_t)b * 4096;
        #pragma unroll
        for (int q = 0; q < 16; ++q) {
            int idx = q * 256 + t;
            multS[idx >> 6][idx & 63] = ms[idx] * ATT_SCALE;
        }
    }

    for (int h = 0; h < 8; ++h) {
        // ---- issue V loads (wave w covers d in [w*16, w*16+16)) ----
        const ushort_t* vrow = qkv + base + (size_t)lane * QKV_LD + 1024 + h * 64 + wave * 16;
        uint4 v0 = *(const uint4*)vrow;
        uint4 v1 = *(const uint4*)(vrow + 8);

        // ---- Q/K fragments direct from global (overlap with V latency) ----
        bf16x8 aq[2], kf[4][2];
        {
            const ushort_t* qb = qkv + base + (size_t)(iw0 + l15) * QKV_LD + h * 64 + g * 8;
            aq[0] = *(const bf16x8*)qb;
            aq[1] = *(const bf16x8*)(qb + 32);
        }
        #pragma unroll
        for (int jj = 0; jj < 4; ++jj) {
            const ushort_t* kb = qkv + base + (size_t)(jj * 16 + l15) * QKV_LD + 512 + h * 64 + g * 8;
            kf[jj][0] = *(const bf16x8*)kb;
            kf[jj][1] = *(const bf16x8*)(kb + 32);
        }

        // ---- transpose-write V^T (2B writes, d fixed per instr -> 2-way, free) ----
        {
            union { uint4 v[2]; ushort_t us[16]; } vu;
            vu.v[0] = v0; vu.v[1] = v1;
            #pragma unroll
            for (int e = 0; e < 16; ++e)
                vt[wave * 16 + e][lane] = vu.us[e];
        }
        __syncthreads();   // vt (and multS on h==0) visible to all waves

        // ---- QK^T: acc[jj] over 4 col tiles, K=64 in 2 steps ----
        f32x4 acc[4];
        #pragma unroll
        for (int jj = 0; jj < 4; ++jj) acc[jj] = (f32x4){0.f, 0.f, 0.f, 0.f};
        #pragma unroll
        for (int kk = 0; kk < 2; ++kk)
            #pragma unroll
            for (int jj = 0; jj < 4; ++jj)
                acc[jj] = __builtin_amdgcn_mfma_f32_16x16x32_bf16(
                    aq[kk], kf[jj][kk], acc[jj], 0, 0, 0);

        // ---- softmax (rows = g*4+r; reduce over 16-lane column group) ----
        float invr[4];
        #pragma unroll
        for (int r = 0; r < 4; ++r) {
            int iw = iw0 + g * 4 + r;
            const float* brow = bias_full + h * 4096 + iw * 64;
            float lg[4];
            #pragma unroll
            for (int jj = 0; jj < 4; ++jj)
                lg[jj] = fmaf(acc[jj][r], multS[iw][jj * 16 + l15], brow[jj * 16 + l15]);
            float mx = fmaxf(fmaxf(lg[0], lg[1]), fmaxf(lg[2], lg[3]));
            #pragma unroll
            for (int s = 1; s <= 8; s <<= 1) mx = fmaxf(mx, __shfl_xor(mx, s));
            float p[4], sum = 0.f;
            #pragma unroll
            for (int jj = 0; jj < 4; ++jj) { p[jj] = __expf(lg[jj] - mx); sum += p[jj]; }
            #pragma unroll
            for (int s = 1; s <= 8; s <<= 1) sum += __shfl_xor(sum, s);
            invr[r] = 1.0f / sum;
            #pragma unroll
            for (int jj = 0; jj < 4; ++jj)
                ps[wave][g * 4 + r][jj * 16 + l15] = f2bf(p[jj]);
        }

        // ---- PV: A = P (own-wave LDS), B = V^T (shared LDS) ----
        f32x4 po[4];
        #pragma unroll
        for (int dt = 0; dt < 4; ++dt) po[dt] = (f32x4){0.f, 0.f, 0.f, 0.f};
        #pragma unroll
        for (int kk = 0; kk < 2; ++kk) {
            bf16x8 pa = *(const bf16x8*)&ps[wave][l15][kk * 32 + g * 8];
            #pragma unroll
            for (int dt = 0; dt < 4; ++dt) {
                bf16x8 vb = *(const bf16x8*)&vt[dt * 16 + l15][kk * 32 + g * 8];
                po[dt] = __builtin_amdgcn_mfma_f32_16x16x32_bf16(pa, vb, po[dt], 0, 0, 0);
            }
        }

        // ---- epilogue: normalize by 1/sum (same lane holds it) and store ----
        #pragma unroll
        for (int dt = 0; dt < 4; ++dt)
            #pragma unroll
            for (int r = 0; r < 4; ++r)
                qkv[base + (size_t)(iw0 + g * 4 + r) * QKV_LD + h * 64 + dt * 16 + l15] =
                    f2bf(po[dt][r] * invr[r]);

        __syncthreads();   // all vt reads done before next head overwrites
    }
}

// ---------------------------------------------------------------------------
// Kernel 4: out = ctx(bf16, LD 1536) @ wproj^T + bproj  (MFMA) — unchanged
// ---------------------------------------------------------------------------
__global__ __launch_bounds__(256) void gemm_proj_mfma(
    const ushort_t* __restrict__ ctx, const float* __restrict__ wproj,
    const float* __restrict__ bproj, float* __restrict__ out)
{
    __shared__ uint4 AsU[512];
    __shared__ uint4 BsU[512];

    int bid = blockIdx.x;
    int bx = bid & 3, by = bid >> 2;
    int row0 = by * 128, col0 = bx * 128;

    int t = threadIdx.x;
    int wave = t >> 6, lane = t & 63;
    int wr = wave >> 1, wc = wave & 1;
    int l15 = lane & 15, kq = lane >> 4;

    f32x4 zero = {0.f, 0.f, 0.f, 0.f};
    f32x4 acc[4][4];
    #pragma unroll
    for (int i = 0; i < 4; ++i)
        #pragma unroll
        for (int j = 0; j < 4; ++j) acc[i][j] = zero;

    for (int k0 = 0; k0 < 512; k0 += 32) {
        #pragma unroll
        for (int q = 0; q < 2; ++q) {
            int c = wave * 128 + q * 64 + lane;
            int m = c >> 2, kg = (c & 3) ^ ((m >> 1) & 3);
            async_copy16(ctx + (size_t)(row0 + m) * QKV_LD + k0 + kg * 8, &AsU[c]);
        }
        #pragma unroll
        for (int q = 0; q < 2; ++q) {
            int c = t + 256 * q;
            int n = c >> 2, kg = (c & 3) ^ ((n >> 1) & 3);
            const float* src = wproj + (size_t)(col0 + n) * 512 + k0 + kg * 8;
            float4 s0 = *(const float4*)src;
            float4 s1 = *(const float4*)(src + 4);
            union { ushort_t us[8]; uint4 v; } p;
            p.us[0] = f2bf(s0.x); p.us[1] = f2bf(s0.y); p.us[2] = f2bf(s0.z); p.us[3] = f2bf(s0.w);
            p.us[4] = f2bf(s1.x); p.us[5] = f2bf(s1.y); p.us[6] = f2bf(s1.z); p.us[7] = f2bf(s1.w);
            BsU[c] = p.v;
        }
        __syncthreads();
        bf16x8 af[4], bf[4];
        #pragma unroll
        for (int ii = 0; ii < 4; ++ii) {
            int M = wr * 64 + ii * 16 + l15;
            af[ii] = *(bf16x8*)&AsU[M * 4 + (kq ^ ((M >> 1) & 3))];
            int Nn = wc * 64 + ii * 16 + l15;
            bf[ii] = *(bf16x8*)&BsU[Nn * 4 + (kq ^ ((Nn >> 1) & 3))];
        }
        #pragma unroll
        for (int ii = 0; ii < 4; ++ii)
            #pragma unroll
            for (int jj = 0; jj < 4; ++jj)
                acc[ii][jj] = __builtin_amdgcn_mfma_f32_16x16x32_bf16(
                    af[ii], bf[jj], acc[ii][jj], 0, 0, 0);
        __syncthreads();
    }

    int crow = kq * 4, ccol = l15;
    #pragma unroll
    for (int ii = 0; ii < 4; ++ii) {
        #pragma unroll
        for (int jj = 0; jj < 4; ++jj) {
            int row = row0 + wr * 64 + ii * 16 + crow;
            int col = col0 + wc * 64 + jj * 16 + ccol;
            float bval = bproj[col];
            #pragma unroll
            for (int r = 0; r < 4; ++r)
                out[(size_t)(row + r) * 512 + col] = acc[ii][jj][r] + bval;
        }
    }
}

extern "C" void kernel_launch(void* const* d_in, const int* in_sizes, int n_in,
                              void* d_out, int out_size, void* d_ws, size_t ws_size,
                              hipStream_t stream)
{
    const float* x      = (const float*)d_in[0];
    const float* dino   = (const float*)d_in[1];
    const float* point  = (const float*)d_in[2];
    const float* sdf    = (const float*)d_in[4];
    const float* normal = (const float*)d_in[5];
    const float* smask  = (const float*)d_in[6];
    const float* cmask  = (const float*)d_in[7];
    const float* wq     = (const float*)d_in[8];
    const float* bq     = (const float*)d_in[9];
    const float* wkv    = (const float*)d_in[10];
    const float* bkv    = (const float*)d_in[11];
    const float* table  = (const float*)d_in[12];
    const float* wproj  = (const float*)d_in[13];
    const float* bproj  = (const float*)d_in[14];

    // Layout: qkv (402 MB) in ws. Scratch parked in d_out (268 MB), consumed
    // before the final proj GEMM overwrites all of d_out:
    //   [0, 134217728)            x_bf16    (67108864 ushorts)
    //   [134217728, 135790592)    wqkv_bf16 (1536x512)
    //   [136314880, 169869312)    mult map  (2048x4096 fp32)
    //   [169869312, 170000384)    bias_full (8x64x64 fp32)
    char* ob = (char*)d_out;
    ushort_t* xbf     = (ushort_t*)ob;
    ushort_t* wqkvbf  = (ushort_t*)(ob + 134217728);
    float*    mult    = (float*)(ob + 136314880);
    float*    biasf   = (float*)(ob + 169869312);
    ushort_t* qkv     = (ushort_t*)d_ws;
    float*    out     = (float*)d_out;

    hipLaunchKernelGGL(convert_x_kernel, dim3(32768), dim3(256), 0, stream, x, xbf);
    hipLaunchKernelGGL(convert_w_kernel, dim3(384), dim3(256), 0, stream, wq, wkv, wqkvbf);
    hipLaunchKernelGGL(bias_expand_kernel, dim3(128), dim3(256), 0, stream, table, biasf);
    hipLaunchKernelGGL(mult_kernel, dim3(NWIN), dim3(256), 0, stream,
                       dino, point, sdf, normal, smask, cmask, mult);
    hipLaunchKernelGGL(gemm_qkv_mfma, dim3(1024 * 12), dim3(256), 0, stream,
                       xbf, wqkvbf, bq, bkv, qkv);
    hipLaunchKernelGGL(attn_mfma_kernel, dim3(NWIN), dim3(256), 0, stream,
                       qkv, mult, biasf);
    hipLaunchKernelGGL(gemm_proj_mfma, dim3(1024 * 4), dim3(256), 0, stream,
                       qkv, wproj, bproj, out);
}